// Round 17
// baseline (521.515 us; speedup 1.0000x reference)
//
#include <hip/hip_runtime.h>
#include <math.h>

// TemporalGraphTower on MI355X (gfx950) — round 17.
// Round-16 config with k_nbr layer-split: blockIdx.z = layer (grid 2048x2x2),
// each block gathers xs and computes ONE layer. Halves per-block critical
// path -> better phase diversity between the 2 resident blocks/CU; deletes
// the inter-layer barrier. Gather issued twice (L2/L3-hot, ~+8us).
// Numerics byte-identical to round 16 (passing, absmax 0.0039).

typedef __bf16 bf16;
typedef __bf16 bf16x8 __attribute__((ext_vector_type(8)));
typedef float f32x4 __attribute__((ext_vector_type(4)));

#define MFMA16(a, b, c) __builtin_amdgcn_mfma_f32_16x16x32_bf16((a), (b), (c), 0, 0, 0)

__device__ __forceinline__ void split2(float v, bf16& hi, bf16& lo) {
  hi = (bf16)v;
  lo = (bf16)(v - (float)hi);
}

__device__ __forceinline__ bf16x8 cvt8(const float* __restrict__ p) {
  float4 a = *(const float4*)p;
  float4 b = *(const float4*)(p + 4);
  bf16x8 r;
  r[0] = (bf16)a.x; r[1] = (bf16)a.y; r[2] = (bf16)a.z; r[3] = (bf16)a.w;
  r[4] = (bf16)b.x; r[5] = (bf16)b.y; r[6] = (bf16)b.z; r[7] = (bf16)b.w;
  return r;
}

typedef const __attribute__((address_space(1))) unsigned int* gptr_t;
typedef __attribute__((address_space(3))) unsigned int* lptr_t;
__device__ __forceinline__ void stage16(const void* g, void* l) {
  __builtin_amdgcn_global_load_lds((gptr_t)g, (lptr_t)l, 16, 0, 0);
}

#define NB_EV 8192
#define ROWS_NB (NB_EV * 20)   // 163840
#define N_NODES 100000
#define IN_DIM 352
#define HID 256
#define ND 128

// ---------------- merged prep: weights + misc + memB + edge_enc ----------
__global__ void k_prep_all(const float* __restrict__ W1, const float* __restrict__ W2,
                           const float* __restrict__ wih, const float* __restrict__ whh,
                           const float* __restrict__ ts, const float* __restrict__ w0,
                           const float* __restrict__ b0, const float* __restrict__ w,
                           const float* __restrict__ bb,
                           const int* __restrict__ srcn, const int* __restrict__ dstn,
                           const float* __restrict__ memory,
                           const float* __restrict__ ea, const float* __restrict__ encW,
                           const float* __restrict__ encb,
                           bf16* __restrict__ W1blk, bf16* __restrict__ W1red,
                           bf16* __restrict__ W2blk,
                           bf16* __restrict__ wihblk, bf16* __restrict__ whhblk,
                           float* __restrict__ w320,
                           float* __restrict__ time_emb, float* __restrict__ embA0,
                           float* __restrict__ embB0, bf16* __restrict__ memB,
                           float* __restrict__ edge_enc) {
  const int NW1 = 2 * 11 * 256 * 32;    // 180224
  const int NW1R = 2 * 7 * 256 * 32;    // 114688
  const int NW2 = 2 * 2 * 8 * 128 * 32; // 131072
  const int NG = 2 * 4 * 384 * 32;      // 98304
  const int NT = NB_EV * 32;            // 262144
  const int NE = NB_EV * ND;            // 1048576
  const int NM = N_NODES * ND / 8;      // 1600000 (bf16x8 chunks)
  const int NEE = NB_EV * 16;           // 131072 (float4 groups)
  int total = NW1 + NW1R + NW2 + NG + NG + 512 + NT + NE + NM + NEE;
  float w0v = w0[0], b0v = b0[0];
  for (int i = blockIdx.x * blockDim.x + threadIdx.x; i < total; i += gridDim.x * blockDim.x) {
    int j = i;
    if (j < NW1) {
      int l = j / 90112, r = j - l * 90112;
      int k0 = r / 8192, r2 = r & 8191;
      int n = r2 >> 5, ko = r2 & 31, k = k0 * 32 + ko;
      W1blk[j] = (bf16)W1[(l * 352 + k) * 256 + n];
    } else if ((j -= NW1) < NW1R) {
      int l = j / 57344, r = j - l * 57344;
      int kq = r / 8192, r2 = r & 8191;
      int n = r2 >> 5, ko = r2 & 31;
      int k = (kq < 4) ? (kq * 32 + ko) : ((kq < 6) ? (256 + (kq - 4) * 32 + ko) : (320 + ko));
      W1red[j] = (bf16)W1[(l * 352 + k) * 256 + n];
    } else if ((j -= NW1R) < NW2) {
      int l = j >> 16, r = j & 65535;
      int plane = r >> 15, r2 = r & 32767;
      int kg = r2 >> 12, r3 = r2 & 4095;
      int n = r3 >> 5, ko = r3 & 31, k = kg * 32 + ko;
      bf16 hi, lo; split2(W2[(l * 256 + k) * 128 + n], hi, lo);
      W2blk[j] = plane ? lo : hi;
    } else if ((j -= NW2) < NG) {
      int plane = j / 49152, r = j - plane * 49152;
      int kg = r / 12288, r2 = r - kg * 12288;
      int n = r2 >> 5, ko = r2 & 31, k = kg * 32 + ko;
      bf16 hi, lo; split2(wih[n * 128 + k], hi, lo);
      wihblk[j] = plane ? lo : hi;
    } else if ((j -= NG) < NG) {
      int plane = j / 49152, r = j - plane * 49152;
      int kg = r / 12288, r2 = r - kg * 12288;
      int n = r2 >> 5, ko = r2 & 31, k = kg * 32 + ko;
      bf16 hi, lo; split2(whh[n * 128 + k], hi, lo);
      whhblk[j] = plane ? lo : hi;
    } else if ((j -= NG) < 512) {
      int l = j >> 8, n = j & 255;
      w320[j] = W1[(l * 352 + 320) * 256 + n];
    } else if ((j -= 512) < NT) {
      int b = j >> 5, c = j & 31;
      float t = ts[b];
      time_emb[j] = (c == 0) ? (w0v * t + b0v) : sinf(w[c - 1] * t + bb[c - 1]);
    } else if ((j -= NT) < NE) {
      int b = j >> 7, c = j & 127;
      embA0[j] = memory[(long)srcn[b] * ND + c];
      embB0[j] = memory[(long)dstn[b] * ND + c];
    } else if ((j -= NE) < NM) {
      bf16x8 v = cvt8(memory + (long)j * 8);
      *(bf16x8*)&memB[(long)j * 8] = v;
    } else {
      j -= NM;
      int b = j >> 4, c4 = (j & 15) * 4;
      const float* row = ea + b * 64;
      float4 s = *(const float4*)&encb[c4];
#pragma unroll 8
      for (int k = 0; k < 64; ++k) {
        float rv = row[k];
        float4 wv = *(const float4*)&encW[k * 64 + c4];
        s.x += rv * wv.x; s.y += rv * wv.y; s.z += rv * wv.z; s.w += rv * wv.w;
      }
      *(float4*)&edge_enc[b * 64 + c4] = s;
    }
  }
}

// per-row prep: nbid/cl arrays + linear bf16 Xlin[side][rg][96] = nbe(64)+t2v(32)
__global__ __launch_bounds__(256) void k_prep_nbr(
    const int* __restrict__ srcn, const int* __restrict__ dstn,
    const int* __restrict__ nbids, const float* __restrict__ nbt,
    const float* __restrict__ nbe,
    const float* __restrict__ w0p, const float* __restrict__ b0p,
    const float* __restrict__ wp, const float* __restrict__ bp,
    bf16* __restrict__ Xlin, int* __restrict__ nbidArr, float* __restrict__ clArr) {
  __shared__ int flat_l[64];
  __shared__ float t_l[64];
  const int tid = threadIdx.x;
  const int side = blockIdx.y;
  const int r0 = blockIdx.x * 64;
  const int* nodes = side ? dstn : srcn;
  if (tid < 64) {
    int rg = r0 + tid;
    int b = rg / 20, k = rg - b * 20;
    int n = nodes[b];
    int flat = n * 20 + k;
    flat_l[tid] = flat;
    nbidArr[side * ROWS_NB + rg] = nbids[flat];
    float t = nbt[flat];
    t_l[tid] = t;
    clArr[side * ROWS_NB + rg] = w0p[0] * t + b0p[0];
  }
  __syncthreads();
  for (int task = tid; task < 64 * 12; task += 256) {
    int r = task / 12, j = task - r * 12;
    bf16x8 v;
    if (j < 8) {
      v = cvt8(nbe + (long)flat_l[r] * 64 + j * 8);
    } else {
      float t = t_l[r];
#pragma unroll
      for (int q = 0; q < 8; ++q) {
        int c = (j - 8) * 8 + q;
        v[q] = (c == 0) ? (bf16)0.f : (bf16)__sinf(wp[c - 1] * t + bp[c - 1]);
      }
    }
    *(bf16x8*)&Xlin[((long)side * ROWS_NB + r0 + r) * 96 + j * 8] = v;
  }
}

// ---------------- Hnode precompute (+ b1 fold) ----------
__global__ __launch_bounds__(256) void k_hnode(
    const int* __restrict__ srcn, const int* __restrict__ dstn,
    const float* __restrict__ memory, const bf16* __restrict__ W1blk,
    const float* __restrict__ b1, float* __restrict__ Hnode) {
  const int tid = threadIdx.x;
  const int wid = tid >> 6, lane = tid & 63;
  const int colq = lane & 15, cq = lane >> 4;
  const int cq8 = cq * 8;
  const int z = blockIdx.y, layer = z >> 1, side = z & 1;
  const int b0 = blockIdx.x * 64;
  const int* nodes = side ? dstn : srcn;

  long node_r[4];
#pragma unroll
  for (int nr = 0; nr < 4; ++nr) node_r[nr] = nodes[b0 + nr * 16 + colq];

  const bf16* W1l = W1blk + layer * 90112 + 4 * 8192 + (wid * 16 + colq) * 32 + cq8;
  f32x4 acc[4][4];
#pragma unroll
  for (int mc = 0; mc < 4; ++mc)
#pragma unroll
    for (int nr = 0; nr < 4; ++nr) acc[mc][nr] = (f32x4){0.f, 0.f, 0.f, 0.f};
#pragma unroll
  for (int k0 = 0; k0 < 4; ++k0) {
    bf16x8 xb[4];
#pragma unroll
    for (int nr = 0; nr < 4; ++nr)
      xb[nr] = cvt8(memory + node_r[nr] * ND + k0 * 32 + cq8);
    bf16x8 wf[4];
#pragma unroll
    for (int mc = 0; mc < 4; ++mc)
      wf[mc] = *(const bf16x8*)(W1l + k0 * 8192 + mc * 2048);
#pragma unroll
    for (int mc = 0; mc < 4; ++mc)
#pragma unroll
      for (int nr = 0; nr < 4; ++nr)
        acc[mc][nr] = MFMA16(wf[mc], xb[nr], acc[mc][nr]);
  }
  const float* b1l = b1 + layer * 256;
#pragma unroll
  for (int mc = 0; mc < 4; ++mc) {
    float4 bv = *(const float4*)&b1l[mc * 64 + wid * 16 + cq * 4];
#pragma unroll
    for (int nr = 0; nr < 4; ++nr) {
      acc[mc][nr][0] += bv.x; acc[mc][nr][1] += bv.y;
      acc[mc][nr][2] += bv.z; acc[mc][nr][3] += bv.w;
      long row = (long)z * NB_EV + b0 + nr * 16 + colq;
      *(f32x4*)&Hnode[row * 256 + mc * 64 + wid * 16 + cq * 4] = acc[mc][nr];
    }
  }
}

// ---------------- fused neighbor kernel: one layer per block -------
// grid (2048, 2 side, 2 layer). LDS: xs 35840 + hhi/hlo [80][136] = 79.4KB.
#define HSS2 136
#define F_XS 0
#define F_HHI 35840
#define F_HLO 57600
#define F_TOT 79360
__global__ __launch_bounds__(256, 2) void k_nbr(
    const bf16* __restrict__ memB, const int* __restrict__ nbidArr,
    const float* __restrict__ clArr, const bf16* __restrict__ Xlin,
    const float* __restrict__ Hnode,
    const bf16* __restrict__ W1red, const bf16* __restrict__ W2blk,
    const float* __restrict__ w320,
    const float* __restrict__ b2, float* __restrict__ nb_out) {
  __shared__ __align__(16) char smem[F_TOT];
  bf16* xs = (bf16*)(smem + F_XS);
  bf16* hhi = (bf16*)(smem + F_HHI);
  bf16* hlo = (bf16*)(smem + F_HLO);

  const int tid = threadIdx.x;
  const int wid = tid >> 6, lane = tid & 63;
  const int colq = lane & 15, cq = lane >> 4;
  const int cq8 = cq * 8;
  const int side = blockIdx.y;
  const int layer = blockIdx.z;
  const int r0 = blockIdx.x * 80;
  const long rowBase = (long)side * ROWS_NB + r0;

  // per-lane direct loads (L2-hot, written by prep): no LDS round-trip
  float clr[5];
  int ev_r[5];
#pragma unroll
  for (int nr = 0; nr < 5; ++nr) {
    int row = nr * 16 + colq;
    clr[nr] = clArr[rowBase + row];
    ev_r[nr] = blockIdx.x * 4 + row / 20;
  }

  // phase B: async global->LDS gather (linear dest, inverse-swizzled source)
  {
#pragma unroll
    for (int q = 0; q < 9; ++q) {
      int i = wid + q * 4;
      if (i >= 35) break;   // uniform per wave
      int s = i * 64 + lane;
      int kq = s / 320, rem = s - kq * 320;
      int r = rem >> 2, swz = rem & 3;
      int k8 = swz ^ (r & 3) ^ ((r >> 2) & 3);
      const bf16* src;
      if (kq < 4) {
        src = memB + (long)nbidArr[rowBase + r] * ND + (kq * 4 + k8) * 8;
      } else {
        int jj = (kq < 6) ? ((kq - 4) * 4 + k8) : (8 + k8);
        src = Xlin + (rowBase + r) * 96 + jj * 8;
      }
      stage16(src, (char*)xs + s * 16);
    }
  }
  __syncthreads();  // drains vmcnt; xs ready

  const int swzr = cq ^ (colq & 3) ^ ((colq >> 2) & 3);

  const bf16* W1l = W1red + layer * 57344 + (wid * 16 + colq) * 32 + cq8;
  const float* Hz = Hnode + ((long)(layer * 2 + side) * NB_EV) * 256;

  // ---- M1-T: acc init from Hnode (b1 pre-folded), preload + PIN W1 strip
  f32x4 acc[4][5];
#pragma unroll
  for (int mc = 0; mc < 4; ++mc)
#pragma unroll
    for (int nr = 0; nr < 5; ++nr)
      acc[mc][nr] = *(const f32x4*)&Hz[(long)ev_r[nr] * 256 + mc * 64 + wid * 16 + cq * 4];

  bf16x8 w1f[7][4];
#pragma unroll
  for (int kq = 0; kq < 7; ++kq)
#pragma unroll
    for (int mc = 0; mc < 4; ++mc)
      w1f[kq][mc] = *(const bf16x8*)(W1l + kq * 8192 + mc * 2048);
#pragma unroll
  for (int kq = 0; kq < 7; ++kq)
#pragma unroll
    for (int mc = 0; mc < 4; ++mc)
      asm volatile("" : "+v"(w1f[kq][mc]));   // pin: forbid re-sinking

#pragma unroll
  for (int kq = 0; kq < 7; ++kq) {
    bf16x8 xb[5];
#pragma unroll
    for (int nr = 0; nr < 5; ++nr)
      xb[nr] = *(const bf16x8*)(xs + kq * 2560 + (nr * 16 + colq) * 32 + swzr * 8);
#pragma unroll
    for (int mc = 0; mc < 4; ++mc)
#pragma unroll
      for (int nr = 0; nr < 5; ++nr)
        acc[mc][nr] = MFMA16(w1f[kq][mc], xb[nr], acc[mc][nr]);
  }

  // rank-1 time fix + relu (b1 already in Hnode)
  const float* w320l = w320 + layer * 256;
#pragma unroll
  for (int mc = 0; mc < 4; ++mc) {
    int c0 = mc * 64 + wid * 16 + cq * 4;
    float4 wv = *(const float4*)&w320l[c0];
#pragma unroll
    for (int nr = 0; nr < 5; ++nr) {
      float c = clr[nr];
      acc[mc][nr][0] = fmaxf(acc[mc][nr][0] + c * wv.x, 0.f);
      acc[mc][nr][1] = fmaxf(acc[mc][nr][1] + c * wv.y, 0.f);
      acc[mc][nr][2] = fmaxf(acc[mc][nr][2] + c * wv.z, 0.f);
      acc[mc][nr][3] = fmaxf(acc[mc][nr][3] + c * wv.w, 0.f);
    }
  }

  const bf16* W2h = W2blk + layer * 65536 + (wid * 32 + colq) * 32 + cq8;
  const bf16* W2l = W2h + 32768;
  f32x4 acc2[2][5];
#pragma unroll
  for (int mc2 = 0; mc2 < 2; ++mc2)
#pragma unroll
    for (int nr = 0; nr < 5; ++nr) acc2[mc2][nr] = (f32x4){0.f, 0.f, 0.f, 0.f};

#pragma unroll
  for (int hh = 0; hh < 2; ++hh) {
    // dump h cols [hh*128, hh*128+128) -> local [0,128)
#pragma unroll
    for (int mq = 0; mq < 2; ++mq) {
      int mc = hh * 2 + mq;
      int cl0 = mq * 64 + wid * 16 + cq * 4;
#pragma unroll
      for (int nr = 0; nr < 5; ++nr) {
        int r = nr * 16 + colq;
        union { bf16 h[4]; uint2 u; } ph, pl;
#pragma unroll
        for (int i = 0; i < 4; ++i) split2(acc[mc][nr][i], ph.h[i], pl.h[i]);
        *(uint2*)&hhi[r * HSS2 + cl0] = ph.u;
        *(uint2*)&hlo[r * HSS2 + cl0] = pl.u;
      }
    }
    __syncthreads();  // dump visible

    // preload + PIN W2 strip for this half (16 frags) — proven balance
    bf16x8 w2hf[4][2], w2lf[4][2];
#pragma unroll
    for (int kq = 0; kq < 4; ++kq)
#pragma unroll
      for (int mc2 = 0; mc2 < 2; ++mc2) {
        w2hf[kq][mc2] = *(const bf16x8*)(W2h + (hh * 4 + kq) * 4096 + mc2 * 512);
        w2lf[kq][mc2] = *(const bf16x8*)(W2l + (hh * 4 + kq) * 4096 + mc2 * 512);
      }
#pragma unroll
    for (int kq = 0; kq < 4; ++kq)
#pragma unroll
      for (int mc2 = 0; mc2 < 2; ++mc2) {
        asm volatile("" : "+v"(w2hf[kq][mc2]));
        asm volatile("" : "+v"(w2lf[kq][mc2]));
      }

#pragma unroll
    for (int kq = 0; kq < 4; ++kq) {
      bf16x8 bh[5], bl[5];
#pragma unroll
      for (int nr = 0; nr < 5; ++nr) {
        int r = nr * 16 + colq;
        bh[nr] = *(const bf16x8*)(hhi + r * HSS2 + kq * 32 + cq8);
        bl[nr] = *(const bf16x8*)(hlo + r * HSS2 + kq * 32 + cq8);
      }
#pragma unroll
      for (int mc2 = 0; mc2 < 2; ++mc2)
#pragma unroll
        for (int nr = 0; nr < 5; ++nr) {
          acc2[mc2][nr] = MFMA16(w2hf[kq][mc2], bh[nr], acc2[mc2][nr]);
          acc2[mc2][nr] = MFMA16(w2lf[kq][mc2], bh[nr], acc2[mc2][nr]);
          acc2[mc2][nr] = MFMA16(w2hf[kq][mc2], bl[nr], acc2[mc2][nr]);
        }
    }
    if (hh == 0) __syncthreads();  // half-0 reads done before half-1 dump
  }

  // ---- segmented mean over k: 4 whole events per 80-row tile, NO atomics
  {
    const float* b2l = b2 + layer * 128;
    long zbase = (long)(layer * 2 + side) * NB_EV * ND;
#pragma unroll
    for (int e = 0; e < 4; ++e) {
      int lo = e * 20, hi = lo + 20;
      f32x4 v[2];
#pragma unroll
      for (int mc2 = 0; mc2 < 2; ++mc2) {
        v[mc2] = (f32x4){0.f, 0.f, 0.f, 0.f};
#pragma unroll
        for (int nr = 0; nr < 5; ++nr) {
          int rl = nr * 16 + colq;
          if (rl >= lo && rl < hi) v[mc2] += acc2[mc2][nr];
        }
      }
#pragma unroll
      for (int s = 1; s < 16; s <<= 1) {
#pragma unroll
        for (int mc2 = 0; mc2 < 2; ++mc2) {
          v[mc2][0] += __shfl_xor(v[mc2][0], s);
          v[mc2][1] += __shfl_xor(v[mc2][1], s);
          v[mc2][2] += __shfl_xor(v[mc2][2], s);
          v[mc2][3] += __shfl_xor(v[mc2][3], s);
        }
      }
      if (colq == e) {
        long b = blockIdx.x * 4 + e;
#pragma unroll
        for (int mc2 = 0; mc2 < 2; ++mc2) {
          int c = wid * 32 + mc2 * 16 + cq * 4;
          float4 bv = *(const float4*)&b2l[c];
          float4 o;
          o.x = (v[mc2][0] + 20.f * bv.x) * 0.05f;
          o.y = (v[mc2][1] + 20.f * bv.y) * 0.05f;
          o.z = (v[mc2][2] + 20.f * bv.z) * 0.05f;
          o.w = (v[mc2][3] + 20.f * bv.w) * 0.05f;
          *(float4*)&nb_out[zbase + b * ND + c] = o;
        }
      }
    }
  }
}

// ---------------- event chain: MLP + GRU (round 16, verbatim) ----------------
#define XSS 360
#define HSS 136
#define E_G 46080
#define E_CL 80896
#define E_TOT 81152
__global__ __launch_bounds__(256, 1) void k_event(
    int layer, const float* __restrict__ embA_in, const float* __restrict__ embB_in,
    float* __restrict__ outA, int ostrideA, float* __restrict__ outB, int ostrideB,
    const float* __restrict__ time_emb, const float* __restrict__ edge_enc,
    const bf16* __restrict__ W1blk, const bf16* __restrict__ W2blk,
    const float* __restrict__ w320, const float* __restrict__ b1,
    const float* __restrict__ b2, const float* __restrict__ nb_out,
    const bf16* __restrict__ wihblk, const bf16* __restrict__ whhblk,
    const float* __restrict__ bih, const float* __restrict__ bhh) {
  __shared__ __align__(16) char smem[E_TOT];
  bf16* xs = (bf16*)(smem);
  bf16* hhi = (bf16*)(smem);
  bf16* hlo = (bf16*)(smem + 17408);
  bf16* mhi = (bf16*)(smem);
  bf16* mlo = (bf16*)(smem + 17408);
  bf16* ghi = (bf16*)(smem + E_G);
  bf16* glo = (bf16*)(smem + E_G + 17408);
  float* cl = (float*)(smem + E_CL);

  const int tid = threadIdx.x;
  const int r0 = blockIdx.x * 64;
  const int side = r0 >> 13;
  const int b0r = r0 & (NB_EV - 1);
  const float* ea = side ? embB_in : embA_in;
  const float* eb = side ? embA_in : embB_in;

  if (tid < 64) cl[tid] = time_emb[(b0r + tid) * 32];

  for (int task = tid; task < 64 * 88; task += 256) {
    int r = task / 88; int c = (task - r * 88) * 4;
    int b = b0r + r;
    float4 v;
    if (c < 128) {
      v = *(const float4*)&ea[(long)b * ND + c];
      bf16 h0, l0, h1, l1, h2, l2, h3, l3;
      split2(v.x, h0, l0); split2(v.y, h1, l1); split2(v.z, h2, l2); split2(v.w, h3, l3);
      ghi[r * HSS + c + 0] = h0; glo[r * HSS + c + 0] = l0;
      ghi[r * HSS + c + 1] = h1; glo[r * HSS + c + 1] = l1;
      ghi[r * HSS + c + 2] = h2; glo[r * HSS + c + 2] = l2;
      ghi[r * HSS + c + 3] = h3; glo[r * HSS + c + 3] = l3;
    } else if (c < 256) {
      v = *(const float4*)&eb[(long)b * ND + (c - 128)];
    } else if (c < 320) {
      v = *(const float4*)&edge_enc[(long)b * 64 + (c - 256)];
    } else {
      float vv[4];
#pragma unroll
      for (int q = 0; q < 4; ++q) {
        int cc = c + q - 320;
        vv[q] = (cc == 0) ? 0.f : time_emb[b * 32 + cc];
      }
      v = make_float4(vv[0], vv[1], vv[2], vv[3]);
    }
    union { bf16 h[4]; uint2 u; } pk;
    pk.h[0] = (bf16)v.x; pk.h[1] = (bf16)v.y; pk.h[2] = (bf16)v.z; pk.h[3] = (bf16)v.w;
    *(uint2*)&xs[r * XSS + c] = pk.u;
  }
  __syncthreads();

  const int wid = tid >> 6, lane = tid & 63;
  const int colq = lane & 15, cq = lane >> 4;
  const int rsub = cq * 4;

  const bf16* W1l = W1blk + layer * 90112 + (wid * 64 + colq) * 32 + cq * 8;
  const bf16* xsl = xs + colq * XSS + cq * 8;
  f32x4 acc[4][4];
#pragma unroll
  for (int m = 0; m < 4; ++m)
#pragma unroll
    for (int n = 0; n < 4; ++n) acc[m][n] = (f32x4){0.f, 0.f, 0.f, 0.f};
#pragma unroll
  for (int k0 = 0; k0 < 11; ++k0) {
    bf16x8 a[4], b[4];
#pragma unroll
    for (int m = 0; m < 4; ++m) a[m] = *(const bf16x8*)(xsl + m * 16 * XSS + k0 * 32);
#pragma unroll
    for (int n = 0; n < 4; ++n) b[n] = *(const bf16x8*)(W1l + k0 * 8192 + n * 512);
#pragma unroll
    for (int m = 0; m < 4; ++m)
#pragma unroll
      for (int n = 0; n < 4; ++n) acc[m][n] = MFMA16(a[m], b[n], acc[m][n]);
  }
  __syncthreads();

  const float* w320l = w320 + layer * 256;
  const float* b1l = b1 + layer * 256;
#pragma unroll
  for (int n = 0; n < 4; ++n) {
    int cg = wid * 64 + n * 16 + colq;
    float wv = w320l[cg], bv = b1l[cg];
#pragma unroll
    for (int m = 0; m < 4; ++m)
#pragma unroll
      for (int i = 0; i < 4; ++i) {
        int r = m * 16 + rsub + i;
        acc[m][n][i] = fmaxf(acc[m][n][i] + cl[r] * wv + bv, 0.f);
      }
  }
  if (wid < 2) {
#pragma unroll
    for (int m = 0; m < 4; ++m)
#pragma unroll
      for (int n = 0; n < 4; ++n)
#pragma unroll
        for (int i = 0; i < 4; ++i) {
          int r = m * 16 + rsub + i;
          int cc = wid * 64 + n * 16 + colq;
          bf16 hi, lo; split2(acc[m][n][i], hi, lo);
          hhi[r * HSS + cc] = hi;
          hlo[r * HSS + cc] = lo;
        }
  }
  __syncthreads();

  const bf16* W2h = W2blk + layer * 65536 + (wid * 32 + colq) * 32 + cq * 8;
  const bf16* W2l = W2h + 32768;
  const bf16* hhil = hhi + colq * HSS + cq * 8;
  const bf16* hlol = hlo + colq * HSS + cq * 8;
  f32x4 acc2[4][2];
#pragma unroll
  for (int m = 0; m < 4; ++m)
#pragma unroll
    for (int n = 0; n < 2; ++n) acc2[m][n] = (f32x4){0.f, 0.f, 0.f, 0.f};
#pragma unroll
  for (int kg = 0; kg < 8; ++kg) {
    if (kg == 4) {
      __syncthreads();
      if (wid >= 2) {
#pragma unroll
        for (int m = 0; m < 4; ++m)
#pragma unroll
          for (int n = 0; n < 4; ++n)
#pragma unroll
            for (int i = 0; i < 4; ++i) {
              int r = m * 16 + rsub + i;
              int cc = (wid & 1) * 64 + n * 16 + colq;
              bf16 hi, lo; split2(acc[m][n][i], hi, lo);
              hhi[r * HSS + cc] = hi;
              hlo[r * HSS + cc] = lo;
            }
      }
      __syncthreads();
    }
    int lk = (kg & 3) * 32;
    bf16x8 ahi[4], alo[4], bhi[2], blo[2];
#pragma unroll
    for (int m = 0; m < 4; ++m) {
      ahi[m] = *(const bf16x8*)(hhil + m * 16 * HSS + lk);
      alo[m] = *(const bf16x8*)(hlol + m * 16 * HSS + lk);
    }
#pragma unroll
    for (int n = 0; n < 2; ++n) {
      bhi[n] = *(const bf16x8*)(W2h + kg * 4096 + n * 512);
      blo[n] = *(const bf16x8*)(W2l + kg * 4096 + n * 512);
    }
#pragma unroll
    for (int m = 0; m < 4; ++m)
#pragma unroll
      for (int n = 0; n < 2; ++n) {
        acc2[m][n] = MFMA16(ahi[m], bhi[n], acc2[m][n]);
        acc2[m][n] = MFMA16(ahi[m], blo[n], acc2[m][n]);
        acc2[m][n] = MFMA16(alo[m], bhi[n], acc2[m][n]);
      }
  }
  __syncthreads();

  const float* b2l = b2 + layer * 128;
  const float* nbl = nb_out + ((long)(layer * 2 + side)) * NB_EV * ND;
#pragma unroll
  for (int n = 0; n < 2; ++n) {
    int cg = wid * 32 + n * 16 + colq;
    float bv = b2l[cg];
#pragma unroll
    for (int m = 0; m < 4; ++m)
#pragma unroll
      for (int i = 0; i < 4; ++i) {
        int r = m * 16 + rsub + i;
        float mval = acc2[m][n][i] + bv + nbl[(long)(b0r + r) * ND + cg];
        bf16 hi, lo; split2(mval, hi, lo);
        mhi[r * HSS + cg] = hi;
        mlo[r * HSS + cg] = lo;
      }
  }
  __syncthreads();

  float* outP = side ? outB : outA;
  const int ostride = side ? ostrideB : ostrideA;
  const int rowA = wid * 16 + colq;
  const int rbase = wid * 16 + rsub;
  const bf16* mhil = mhi + rowA * HSS + cq * 8;
  const bf16* mlol = mlo + rowA * HSS + cq * 8;
  const bf16* ghil = ghi + rowA * HSS + cq * 8;
  const bf16* glol = glo + rowA * HSS + cq * 8;
  const bf16* wihl = wihblk + colq * 32 + cq * 8;
  const bf16* whhl = whhblk + colq * 32 + cq * 8;

  for (int jt = 0; jt < 8; ++jt) {
    f32x4 gx[3], gh[3];
#pragma unroll
    for (int g = 0; g < 3; ++g) {
      gx[g] = (f32x4){0.f, 0.f, 0.f, 0.f};
      gh[g] = (f32x4){0.f, 0.f, 0.f, 0.f};
    }
#pragma unroll
    for (int kc = 0; kc < 4; ++kc) {
      bf16x8 amh = *(const bf16x8*)(mhil + kc * 32);
      bf16x8 aml = *(const bf16x8*)(mlol + kc * 32);
      bf16x8 ahh = *(const bf16x8*)(ghil + kc * 32);
      bf16x8 ahl = *(const bf16x8*)(glol + kc * 32);
#pragma unroll
      for (int g = 0; g < 3; ++g) {
        int nb = (g * 128 + jt * 16) * 32;
        bf16x8 bh = *(const bf16x8*)(wihl + kc * 12288 + nb);
        bf16x8 bl = *(const bf16x8*)(wihl + 49152 + kc * 12288 + nb);
        gx[g] = MFMA16(amh, bh, gx[g]);
        gx[g] = MFMA16(aml, bh, gx[g]);
        gx[g] = MFMA16(amh, bl, gx[g]);
        bf16x8 ch = *(const bf16x8*)(whhl + kc * 12288 + nb);
        bf16x8 cl2 = *(const bf16x8*)(whhl + 49152 + kc * 12288 + nb);
        gh[g] = MFMA16(ahh, ch, gh[g]);
        gh[g] = MFMA16(ahl, ch, gh[g]);
        gh[g] = MFMA16(ahh, cl2, gh[g]);
      }
    }
    int j = jt * 16 + colq;
    float bihr = bih[j], bihz = bih[128 + j], bihn = bih[256 + j];
    float bhhr = bhh[j], bhhz = bhh[128 + j], bhhn = bhh[256 + j];
#pragma unroll
    for (int i = 0; i < 4; ++i) {
      int rr = rbase + i;
      float rx = gx[0][i] + bihr, zx = gx[1][i] + bihz, nx = gx[2][i] + bihn;
      float rh = gh[0][i] + bhhr, zh = gh[1][i] + bhhz, nh = gh[2][i] + bhhn;
      float r = 1.f / (1.f + expf(-(rx + rh)));
      float zz = 1.f / (1.f + expf(-(zx + zh)));
      float n = tanhf(nx + r * nh);
      float hval = (float)ghi[rr * HSS + j] + (float)glo[rr * HSS + j];
      outP[(long)(b0r + rr) * ostride + j] = (1.f - zz) * n + zz * hval;
    }
  }
}

// ---------------- launch ----------------
extern "C" void kernel_launch(void* const* d_in, const int* in_sizes, int n_in,
                              void* d_out, int out_size, void* d_ws, size_t ws_size,
                              hipStream_t stream) {
  const int* srcn = (const int*)d_in[0];
  const int* dstn = (const int*)d_in[1];
  const float* edge_attrs = (const float*)d_in[2];
  const float* timestamps = (const float*)d_in[3];
  const float* memory = (const float*)d_in[4];
  const int* neighbor_ids = (const int*)d_in[5];
  const float* neighbor_times = (const float*)d_in[6];
  const float* neighbor_edge_attrs = (const float*)d_in[7];
  const float* t2v_w0 = (const float*)d_in[8];
  const float* t2v_b0 = (const float*)d_in[9];
  const float* t2v_w = (const float*)d_in[10];
  const float* t2v_b = (const float*)d_in[11];
  const float* enc_W = (const float*)d_in[12];
  const float* enc_b = (const float*)d_in[13];
  const float* mlp_W1 = (const float*)d_in[14];
  const float* mlp_b1 = (const float*)d_in[15];
  const float* mlp_W2 = (const float*)d_in[16];
  const float* mlp_b2 = (const float*)d_in[17];
  const float* gru_w_ih = (const float*)d_in[18];
  const float* gru_w_hh = (const float*)d_in[19];
  const float* gru_b_ih = (const float*)d_in[20];
  const float* gru_b_hh = (const float*)d_in[21];

  char* ws = (char*)d_ws;
  size_t off = 0;
  auto alloc = [&](size_t bytes) { size_t o = off; off += (bytes + 255) & ~(size_t)255; return o; };
  bf16* W1blk = (bf16*)(ws + alloc((size_t)2 * 11 * 256 * 32 * 2));
  bf16* W1red = (bf16*)(ws + alloc((size_t)2 * 7 * 256 * 32 * 2));
  bf16* W2blk = (bf16*)(ws + alloc((size_t)2 * 2 * 8 * 128 * 32 * 2));
  bf16* wihblk = (bf16*)(ws + alloc((size_t)2 * 4 * 384 * 32 * 2));
  bf16* whhblk = (bf16*)(ws + alloc((size_t)2 * 4 * 384 * 32 * 2));
  float* w320 = (float*)(ws + alloc(512 * 4));
  float* time_emb = (float*)(ws + alloc((size_t)NB_EV * 32 * 4));
  float* edge_enc = (float*)(ws + alloc((size_t)NB_EV * 64 * 4));
  float* embA0 = (float*)(ws + alloc((size_t)NB_EV * ND * 4));
  float* embB0 = (float*)(ws + alloc((size_t)NB_EV * ND * 4));
  float* embA1 = (float*)(ws + alloc((size_t)NB_EV * ND * 4));
  float* embB1 = (float*)(ws + alloc((size_t)NB_EV * ND * 4));
  float* nb_out = (float*)(ws + alloc((size_t)4 * NB_EV * ND * 4));
  float* Hnode = (float*)(ws + alloc((size_t)4 * NB_EV * 256 * 4));
  bf16* memB = (bf16*)(ws + alloc((size_t)N_NODES * ND * 2));
  bf16* Xlin = (bf16*)(ws + alloc((size_t)2 * ROWS_NB * 96 * 2));
  int* nbidArr = (int*)(ws + alloc((size_t)2 * ROWS_NB * 4));
  float* clArr = (float*)(ws + alloc((size_t)2 * ROWS_NB * 4));

  k_prep_all<<<2048, 256, 0, stream>>>(
      mlp_W1, mlp_W2, gru_w_ih, gru_w_hh,
      timestamps, t2v_w0, t2v_b0, t2v_w, t2v_b,
      srcn, dstn, memory, edge_attrs, enc_W, enc_b,
      W1blk, W1red, W2blk, wihblk, whhblk, w320,
      time_emb, embA0, embB0, memB, edge_enc);
  k_prep_nbr<<<dim3(2560, 2, 1), 256, 0, stream>>>(
      srcn, dstn, neighbor_ids, neighbor_times, neighbor_edge_attrs,
      t2v_w0, t2v_b0, t2v_w, t2v_b, Xlin, nbidArr, clArr);
  k_hnode<<<dim3(128, 4, 1), 256, 0, stream>>>(srcn, dstn, memory, W1blk, mlp_b1, Hnode);

  k_nbr<<<dim3(ROWS_NB / 80, 2, 2), 256, 0, stream>>>(
      memB, nbidArr, clArr, Xlin, Hnode, W1red, W2blk, w320, mlp_b2, nb_out);

  k_event<<<2 * NB_EV / 64, 256, 0, stream>>>(
      0, embA0, embB0, embA1, ND, embB1, ND, time_emb, edge_enc,
      W1blk, W2blk, w320, mlp_b1, mlp_b2, nb_out,
      wihblk, whhblk, gru_b_ih, gru_b_hh);

  float* outf = (float*)d_out;
  k_event<<<2 * NB_EV / 64, 256, 0, stream>>>(
      1, embA1, embB1, outf, 2 * ND, outf + ND, 2 * ND, time_emb, edge_enc,
      W1blk, W2blk, w320, mlp_b1, mlp_b2, nb_out,
      wihblk, whhblk, gru_b_ih, gru_b_hh);
}

// Round 18
// 498.024 us; speedup vs baseline: 1.0472x; 1.0472x over previous
//
#include <hip/hip_runtime.h>
#include <math.h>

// TemporalGraphTower on MI355X (gfx950) — FINAL (= round 12, empirical best
// 498.7us; rounds 12/14/16/17 = 499/502/508/522 -> converged noise band).
// Structure: fused k_nbr (async global_load_lds gather -> swizzled LDS,
// Hnode-hoisted M1 with pinned W1 strip, split-half M2 with pinned W2
// strips, register shuffle mean, 80-row atomic-free tiles), prep chain
// (merged elementwise prep + nbr-row prep + Hnode), bf16 hi/lo 3-product
// numerics with fp32 rank-1 time-column fix (absmax 0.0039 vs 2e-2).

typedef __bf16 bf16;
typedef __bf16 bf16x8 __attribute__((ext_vector_type(8)));
typedef float f32x4 __attribute__((ext_vector_type(4)));

#define MFMA16(a, b, c) __builtin_amdgcn_mfma_f32_16x16x32_bf16((a), (b), (c), 0, 0, 0)

__device__ __forceinline__ void split2(float v, bf16& hi, bf16& lo) {
  hi = (bf16)v;
  lo = (bf16)(v - (float)hi);
}

__device__ __forceinline__ bf16x8 cvt8(const float* __restrict__ p) {
  float4 a = *(const float4*)p;
  float4 b = *(const float4*)(p + 4);
  bf16x8 r;
  r[0] = (bf16)a.x; r[1] = (bf16)a.y; r[2] = (bf16)a.z; r[3] = (bf16)a.w;
  r[4] = (bf16)b.x; r[5] = (bf16)b.y; r[6] = (bf16)b.z; r[7] = (bf16)b.w;
  return r;
}

typedef const __attribute__((address_space(1))) unsigned int* gptr_t;
typedef __attribute__((address_space(3))) unsigned int* lptr_t;
__device__ __forceinline__ void stage16(const void* g, void* l) {
  __builtin_amdgcn_global_load_lds((gptr_t)g, (lptr_t)l, 16, 0, 0);
}

#define NB_EV 8192
#define ROWS_NB (NB_EV * 20)   // 163840
#define N_NODES 100000
#define IN_DIM 352
#define HID 256
#define ND 128

// ---------------- merged prep: weights + misc + memB + edge_enc ----------
__global__ void k_prep_all(const float* __restrict__ W1, const float* __restrict__ W2,
                           const float* __restrict__ wih, const float* __restrict__ whh,
                           const float* __restrict__ ts, const float* __restrict__ w0,
                           const float* __restrict__ b0, const float* __restrict__ w,
                           const float* __restrict__ bb,
                           const int* __restrict__ srcn, const int* __restrict__ dstn,
                           const float* __restrict__ memory,
                           const float* __restrict__ ea, const float* __restrict__ encW,
                           const float* __restrict__ encb,
                           bf16* __restrict__ W1blk, bf16* __restrict__ W1red,
                           bf16* __restrict__ W2blk,
                           bf16* __restrict__ wihblk, bf16* __restrict__ whhblk,
                           float* __restrict__ w320,
                           float* __restrict__ time_emb, float* __restrict__ embA0,
                           float* __restrict__ embB0, bf16* __restrict__ memB,
                           float* __restrict__ edge_enc) {
  const int NW1 = 2 * 11 * 256 * 32;    // 180224
  const int NW1R = 2 * 7 * 256 * 32;    // 114688
  const int NW2 = 2 * 2 * 8 * 128 * 32; // 131072
  const int NG = 2 * 4 * 384 * 32;      // 98304
  const int NT = NB_EV * 32;            // 262144
  const int NE = NB_EV * ND;            // 1048576
  const int NM = N_NODES * ND / 8;      // 1600000 (bf16x8 chunks)
  const int NEE = NB_EV * 64;           // 524288
  int total = NW1 + NW1R + NW2 + NG + NG + 512 + NT + NE + NM + NEE;
  float w0v = w0[0], b0v = b0[0];
  for (int i = blockIdx.x * blockDim.x + threadIdx.x; i < total; i += gridDim.x * blockDim.x) {
    int j = i;
    if (j < NW1) {
      int l = j / 90112, r = j - l * 90112;
      int k0 = r / 8192, r2 = r & 8191;
      int n = r2 >> 5, ko = r2 & 31, k = k0 * 32 + ko;
      W1blk[j] = (bf16)W1[(l * 352 + k) * 256 + n];
    } else if ((j -= NW1) < NW1R) {
      int l = j / 57344, r = j - l * 57344;
      int kq = r / 8192, r2 = r & 8191;
      int n = r2 >> 5, ko = r2 & 31;
      int k = (kq < 4) ? (kq * 32 + ko) : ((kq < 6) ? (256 + (kq - 4) * 32 + ko) : (320 + ko));
      W1red[j] = (bf16)W1[(l * 352 + k) * 256 + n];
    } else if ((j -= NW1R) < NW2) {
      int l = j >> 16, r = j & 65535;
      int plane = r >> 15, r2 = r & 32767;
      int kg = r2 >> 12, r3 = r2 & 4095;
      int n = r3 >> 5, ko = r3 & 31, k = kg * 32 + ko;
      bf16 hi, lo; split2(W2[(l * 256 + k) * 128 + n], hi, lo);
      W2blk[j] = plane ? lo : hi;
    } else if ((j -= NW2) < NG) {
      int plane = j / 49152, r = j - plane * 49152;
      int kg = r / 12288, r2 = r - kg * 12288;
      int n = r2 >> 5, ko = r2 & 31, k = kg * 32 + ko;
      bf16 hi, lo; split2(wih[n * 128 + k], hi, lo);
      wihblk[j] = plane ? lo : hi;
    } else if ((j -= NG) < NG) {
      int plane = j / 49152, r = j - plane * 49152;
      int kg = r / 12288, r2 = r - kg * 12288;
      int n = r2 >> 5, ko = r2 & 31, k = kg * 32 + ko;
      bf16 hi, lo; split2(whh[n * 128 + k], hi, lo);
      whhblk[j] = plane ? lo : hi;
    } else if ((j -= NG) < 512) {
      int l = j >> 8, n = j & 255;
      w320[j] = W1[(l * 352 + 320) * 256 + n];
    } else if ((j -= 512) < NT) {
      int b = j >> 5, c = j & 31;
      float t = ts[b];
      time_emb[j] = (c == 0) ? (w0v * t + b0v) : sinf(w[c - 1] * t + bb[c - 1]);
    } else if ((j -= NT) < NE) {
      int b = j >> 7, c = j & 127;
      embA0[j] = memory[(long)srcn[b] * ND + c];
      embB0[j] = memory[(long)dstn[b] * ND + c];
    } else if ((j -= NE) < NM) {
      bf16x8 v = cvt8(memory + (long)j * 8);
      *(bf16x8*)&memB[(long)j * 8] = v;
    } else {
      j -= NM;
      int b = j >> 6, c = j & 63;
      float s = encb[c];
      const float* row = ea + b * 64;
#pragma unroll 8
      for (int k = 0; k < 64; ++k) s += row[k] * encW[k * 64 + c];
      edge_enc[j] = s;
    }
  }
}

// per-row prep: nbid/cl arrays + linear bf16 Xlin[side][rg][96] = nbe(64)+t2v(32)
__global__ __launch_bounds__(256) void k_prep_nbr(
    const int* __restrict__ srcn, const int* __restrict__ dstn,
    const int* __restrict__ nbids, const float* __restrict__ nbt,
    const float* __restrict__ nbe,
    const float* __restrict__ w0p, const float* __restrict__ b0p,
    const float* __restrict__ wp, const float* __restrict__ bp,
    bf16* __restrict__ Xlin, int* __restrict__ nbidArr, float* __restrict__ clArr) {
  __shared__ int flat_l[64];
  __shared__ float t_l[64];
  const int tid = threadIdx.x;
  const int side = blockIdx.y;
  const int r0 = blockIdx.x * 64;
  const int* nodes = side ? dstn : srcn;
  if (tid < 64) {
    int rg = r0 + tid;
    int b = rg / 20, k = rg - b * 20;
    int n = nodes[b];
    int flat = n * 20 + k;
    flat_l[tid] = flat;
    nbidArr[side * ROWS_NB + rg] = nbids[flat];
    float t = nbt[flat];
    t_l[tid] = t;
    clArr[side * ROWS_NB + rg] = w0p[0] * t + b0p[0];
  }
  __syncthreads();
  for (int task = tid; task < 64 * 12; task += 256) {
    int r = task / 12, j = task - r * 12;
    bf16x8 v;
    if (j < 8) {
      v = cvt8(nbe + (long)flat_l[r] * 64 + j * 8);
    } else {
      float t = t_l[r];
#pragma unroll
      for (int q = 0; q < 8; ++q) {
        int c = (j - 8) * 8 + q;
        v[q] = (c == 0) ? (bf16)0.f : (bf16)__sinf(wp[c - 1] * t + bp[c - 1]);
      }
    }
    *(bf16x8*)&Xlin[((long)side * ROWS_NB + r0 + r) * 96 + j * 8] = v;
  }
}

// ---------------- Hnode precompute: memory[node] @ W1[128:256] ----------
__global__ __launch_bounds__(256) void k_hnode(
    const int* __restrict__ srcn, const int* __restrict__ dstn,
    const float* __restrict__ memory, const bf16* __restrict__ W1blk,
    float* __restrict__ Hnode) {
  const int tid = threadIdx.x;
  const int wid = tid >> 6, lane = tid & 63;
  const int colq = lane & 15, cq = lane >> 4;
  const int cq8 = cq * 8;
  const int z = blockIdx.y, layer = z >> 1, side = z & 1;
  const int b0 = blockIdx.x * 64;
  const int* nodes = side ? dstn : srcn;

  long node_r[4];
#pragma unroll
  for (int nr = 0; nr < 4; ++nr) node_r[nr] = nodes[b0 + nr * 16 + colq];

  const bf16* W1l = W1blk + layer * 90112 + 4 * 8192 + (wid * 16 + colq) * 32 + cq8;
  f32x4 acc[4][4];
#pragma unroll
  for (int mc = 0; mc < 4; ++mc)
#pragma unroll
    for (int nr = 0; nr < 4; ++nr) acc[mc][nr] = (f32x4){0.f, 0.f, 0.f, 0.f};
#pragma unroll
  for (int k0 = 0; k0 < 4; ++k0) {
    bf16x8 xb[4];
#pragma unroll
    for (int nr = 0; nr < 4; ++nr)
      xb[nr] = cvt8(memory + node_r[nr] * ND + k0 * 32 + cq8);
    bf16x8 wf[4];
#pragma unroll
    for (int mc = 0; mc < 4; ++mc)
      wf[mc] = *(const bf16x8*)(W1l + k0 * 8192 + mc * 2048);
#pragma unroll
    for (int mc = 0; mc < 4; ++mc)
#pragma unroll
      for (int nr = 0; nr < 4; ++nr)
        acc[mc][nr] = MFMA16(wf[mc], xb[nr], acc[mc][nr]);
  }
#pragma unroll
  for (int mc = 0; mc < 4; ++mc)
#pragma unroll
    for (int nr = 0; nr < 4; ++nr) {
      long row = (long)z * NB_EV + b0 + nr * 16 + colq;
      *(f32x4*)&Hnode[row * 256 + mc * 64 + wid * 16 + cq * 4] = acc[mc][nr];
    }
}

// ---------------- fused neighbor kernel: 80-row tiles, atomic-free -------
// LDS: xs [7][80][32] swizzled (35840) + hhi/hlo [80][136] + cl = 79.7KB.
#define HSS2 136
#define F_XS 0
#define F_HHI 35840
#define F_HLO 57600
#define F_CL 79360
#define F_TOT 79680
__global__ __launch_bounds__(256, 2) void k_nbr(
    const bf16* __restrict__ memB, const int* __restrict__ nbidArr,
    const float* __restrict__ clArr, const bf16* __restrict__ Xlin,
    const float* __restrict__ Hnode,
    const bf16* __restrict__ W1red, const bf16* __restrict__ W2blk,
    const float* __restrict__ w320, const float* __restrict__ b1,
    const float* __restrict__ b2, float* __restrict__ nb_out) {
  __shared__ __align__(16) char smem[F_TOT];
  bf16* xs = (bf16*)(smem + F_XS);
  bf16* hhi = (bf16*)(smem + F_HHI);
  bf16* hlo = (bf16*)(smem + F_HLO);
  float* cl = (float*)(smem + F_CL);
  int* nbid_l = (int*)(smem + F_HHI);   // overlay (h unused during gather)

  const int tid = threadIdx.x;
  const int wid = tid >> 6, lane = tid & 63;
  const int colq = lane & 15, cq = lane >> 4;
  const int cq8 = cq * 8;
  const int side = blockIdx.y;
  const int r0 = blockIdx.x * 80;

  // phase A: staged per-row ids + linear time term (precomputed)
  if (tid < 80) {
    nbid_l[tid] = nbidArr[side * ROWS_NB + r0 + tid];
    cl[tid] = clArr[side * ROWS_NB + r0 + tid];
  }
  __syncthreads();  // bar1

  float clr[5];
  int ev_r[5];
#pragma unroll
  for (int nr = 0; nr < 5; ++nr) {
    int row = nr * 16 + colq;
    clr[nr] = cl[row];
    ev_r[nr] = blockIdx.x * 4 + row / 20;
  }

  // phase B: async global->LDS gather. LDS dest linear slot*16; source is the
  // inverse-swizzled global chunk. 35 wave-instructions, all in flight.
  {
    const long xrow = (long)side * ROWS_NB + r0;
#pragma unroll
    for (int q = 0; q < 9; ++q) {
      int i = wid + q * 4;
      if (i >= 35) break;   // uniform per wave
      int s = i * 64 + lane;
      int kq = s / 320, rem = s - kq * 320;
      int r = rem >> 2, swz = rem & 3;
      int k8 = swz ^ (r & 3) ^ ((r >> 2) & 3);
      const bf16* src;
      if (kq < 4) {
        src = memB + (long)nbid_l[r] * ND + (kq * 4 + k8) * 8;
      } else {
        int jj = (kq < 6) ? ((kq - 4) * 4 + k8) : (8 + k8);
        src = Xlin + (xrow + r) * 96 + jj * 8;
      }
      stage16(src, (char*)xs + s * 16);
    }
  }
  __syncthreads();  // bar2 (drains vmcnt)

  const int swzr = cq ^ (colq & 3) ^ ((colq >> 2) & 3);

#pragma unroll
  for (int layer = 0; layer < 2; ++layer) {
    const bf16* W1l = W1red + layer * 57344 + (wid * 16 + colq) * 32 + cq8;
    const float* Hz = Hnode + ((long)(layer * 2 + side) * NB_EV) * 256;

    // ---- M1-T: acc init from Hnode, preload + PIN full W1 strip
    f32x4 acc[4][5];
#pragma unroll
    for (int mc = 0; mc < 4; ++mc)
#pragma unroll
      for (int nr = 0; nr < 5; ++nr)
        acc[mc][nr] = *(const f32x4*)&Hz[(long)ev_r[nr] * 256 + mc * 64 + wid * 16 + cq * 4];

    bf16x8 w1f[7][4];
#pragma unroll
    for (int kq = 0; kq < 7; ++kq)
#pragma unroll
      for (int mc = 0; mc < 4; ++mc)
        w1f[kq][mc] = *(const bf16x8*)(W1l + kq * 8192 + mc * 2048);
#pragma unroll
    for (int kq = 0; kq < 7; ++kq)
#pragma unroll
      for (int mc = 0; mc < 4; ++mc)
        asm volatile("" : "+v"(w1f[kq][mc]));   // pin: forbid re-sinking

#pragma unroll
    for (int kq = 0; kq < 7; ++kq) {
      bf16x8 xb[5];
#pragma unroll
      for (int nr = 0; nr < 5; ++nr)
        xb[nr] = *(const bf16x8*)(xs + kq * 2560 + (nr * 16 + colq) * 32 + swzr * 8);
#pragma unroll
      for (int mc = 0; mc < 4; ++mc)
#pragma unroll
        for (int nr = 0; nr < 5; ++nr)
          acc[mc][nr] = MFMA16(w1f[kq][mc], xb[nr], acc[mc][nr]);
    }

    // rank-1 time fix + bias + relu
    const float* w320l = w320 + layer * 256;
    const float* b1l = b1 + layer * 256;
#pragma unroll
    for (int mc = 0; mc < 4; ++mc) {
      int c0 = mc * 64 + wid * 16 + cq * 4;
      float4 wv = *(const float4*)&w320l[c0];
      float4 bv = *(const float4*)&b1l[c0];
#pragma unroll
      for (int nr = 0; nr < 5; ++nr) {
        float c = clr[nr];
        acc[mc][nr][0] = fmaxf(acc[mc][nr][0] + c * wv.x + bv.x, 0.f);
        acc[mc][nr][1] = fmaxf(acc[mc][nr][1] + c * wv.y + bv.y, 0.f);
        acc[mc][nr][2] = fmaxf(acc[mc][nr][2] + c * wv.z + bv.z, 0.f);
        acc[mc][nr][3] = fmaxf(acc[mc][nr][3] + c * wv.w + bv.w, 0.f);
      }
    }

    if (layer == 1) __syncthreads();  // layer-0 M2 h reads done

    const bf16* W2h = W2blk + layer * 65536 + (wid * 32 + colq) * 32 + cq8;
    const bf16* W2l = W2h + 32768;
    f32x4 acc2[2][5];
#pragma unroll
    for (int mc2 = 0; mc2 < 2; ++mc2)
#pragma unroll
      for (int nr = 0; nr < 5; ++nr) acc2[mc2][nr] = (f32x4){0.f, 0.f, 0.f, 0.f};

#pragma unroll
    for (int hh = 0; hh < 2; ++hh) {
      // dump h cols [hh*128, hh*128+128) -> local [0,128)
#pragma unroll
      for (int mq = 0; mq < 2; ++mq) {
        int mc = hh * 2 + mq;
        int cl0 = mq * 64 + wid * 16 + cq * 4;
#pragma unroll
        for (int nr = 0; nr < 5; ++nr) {
          int r = nr * 16 + colq;
          union { bf16 h[4]; uint2 u; } ph, pl;
#pragma unroll
          for (int i = 0; i < 4; ++i) split2(acc[mc][nr][i], ph.h[i], pl.h[i]);
          *(uint2*)&hhi[r * HSS2 + cl0] = ph.u;
          *(uint2*)&hlo[r * HSS2 + cl0] = pl.u;
        }
      }
      __syncthreads();  // dump visible

      // preload + PIN W2 strip for this half (16 frags)
      bf16x8 w2hf[4][2], w2lf[4][2];
#pragma unroll
      for (int kq = 0; kq < 4; ++kq)
#pragma unroll
        for (int mc2 = 0; mc2 < 2; ++mc2) {
          w2hf[kq][mc2] = *(const bf16x8*)(W2h + (hh * 4 + kq) * 4096 + mc2 * 512);
          w2lf[kq][mc2] = *(const bf16x8*)(W2l + (hh * 4 + kq) * 4096 + mc2 * 512);
        }
#pragma unroll
      for (int kq = 0; kq < 4; ++kq)
#pragma unroll
        for (int mc2 = 0; mc2 < 2; ++mc2) {
          asm volatile("" : "+v"(w2hf[kq][mc2]));
          asm volatile("" : "+v"(w2lf[kq][mc2]));
        }

#pragma unroll
      for (int kq = 0; kq < 4; ++kq) {
        bf16x8 bh[5], bl[5];
#pragma unroll
        for (int nr = 0; nr < 5; ++nr) {
          int r = nr * 16 + colq;
          bh[nr] = *(const bf16x8*)(hhi + r * HSS2 + kq * 32 + cq8);
          bl[nr] = *(const bf16x8*)(hlo + r * HSS2 + kq * 32 + cq8);
        }
#pragma unroll
        for (int mc2 = 0; mc2 < 2; ++mc2)
#pragma unroll
          for (int nr = 0; nr < 5; ++nr) {
            acc2[mc2][nr] = MFMA16(w2hf[kq][mc2], bh[nr], acc2[mc2][nr]);
            acc2[mc2][nr] = MFMA16(w2lf[kq][mc2], bh[nr], acc2[mc2][nr]);
            acc2[mc2][nr] = MFMA16(w2hf[kq][mc2], bl[nr], acc2[mc2][nr]);
          }
      }
      if (hh == 0) __syncthreads();  // half-0 reads done before half-1 dump
    }

    // ---- segmented mean over k: 4 whole events per 80-row tile, NO atomics
    {
      const float* b2l = b2 + layer * 128;
      long zbase = (long)(layer * 2 + side) * NB_EV * ND;
#pragma unroll
      for (int e = 0; e < 4; ++e) {
        int lo = e * 20, hi = lo + 20;
        f32x4 v[2];
#pragma unroll
        for (int mc2 = 0; mc2 < 2; ++mc2) {
          v[mc2] = (f32x4){0.f, 0.f, 0.f, 0.f};
#pragma unroll
          for (int nr = 0; nr < 5; ++nr) {
            int rl = nr * 16 + colq;
            if (rl >= lo && rl < hi) v[mc2] += acc2[mc2][nr];
          }
        }
#pragma unroll
        for (int s = 1; s < 16; s <<= 1) {
#pragma unroll
          for (int mc2 = 0; mc2 < 2; ++mc2) {
            v[mc2][0] += __shfl_xor(v[mc2][0], s);
            v[mc2][1] += __shfl_xor(v[mc2][1], s);
            v[mc2][2] += __shfl_xor(v[mc2][2], s);
            v[mc2][3] += __shfl_xor(v[mc2][3], s);
          }
        }
        if (colq == e) {
          long b = blockIdx.x * 4 + e;
#pragma unroll
          for (int mc2 = 0; mc2 < 2; ++mc2) {
            int c = wid * 32 + mc2 * 16 + cq * 4;
            float4 bv = *(const float4*)&b2l[c];
            float4 o;
            o.x = (v[mc2][0] + 20.f * bv.x) * 0.05f;
            o.y = (v[mc2][1] + 20.f * bv.y) * 0.05f;
            o.z = (v[mc2][2] + 20.f * bv.z) * 0.05f;
            o.w = (v[mc2][3] + 20.f * bv.w) * 0.05f;
            *(float4*)&nb_out[zbase + b * ND + c] = o;
          }
        }
      }
    }
  }
}

// ---------------- event chain: MLP + GRU ----------------
#define XSS 360
#define HSS 136
#define E_G 46080
#define E_CL 80896
#define E_TOT 81152
__global__ __launch_bounds__(256, 1) void k_event(
    int layer, const float* __restrict__ embA_in, const float* __restrict__ embB_in,
    float* __restrict__ outA, int ostrideA, float* __restrict__ outB, int ostrideB,
    const float* __restrict__ time_emb, const float* __restrict__ edge_enc,
    const bf16* __restrict__ W1blk, const bf16* __restrict__ W2blk,
    const float* __restrict__ w320, const float* __restrict__ b1,
    const float* __restrict__ b2, const float* __restrict__ nb_out,
    const bf16* __restrict__ wihblk, const bf16* __restrict__ whhblk,
    const float* __restrict__ bih, const float* __restrict__ bhh) {
  __shared__ __align__(16) char smem[E_TOT];
  bf16* xs = (bf16*)(smem);
  bf16* hhi = (bf16*)(smem);
  bf16* hlo = (bf16*)(smem + 17408);
  bf16* mhi = (bf16*)(smem);
  bf16* mlo = (bf16*)(smem + 17408);
  bf16* ghi = (bf16*)(smem + E_G);
  bf16* glo = (bf16*)(smem + E_G + 17408);
  float* cl = (float*)(smem + E_CL);

  const int tid = threadIdx.x;
  const int r0 = blockIdx.x * 64;
  const int side = r0 >> 13;
  const int b0r = r0 & (NB_EV - 1);
  const float* ea = side ? embB_in : embA_in;
  const float* eb = side ? embA_in : embB_in;

  if (tid < 64) cl[tid] = time_emb[(b0r + tid) * 32];

  for (int task = tid; task < 64 * 88; task += 256) {
    int r = task / 88; int c = (task - r * 88) * 4;
    int b = b0r + r;
    float4 v;
    if (c < 128) {
      v = *(const float4*)&ea[(long)b * ND + c];
      bf16 h0, l0, h1, l1, h2, l2, h3, l3;
      split2(v.x, h0, l0); split2(v.y, h1, l1); split2(v.z, h2, l2); split2(v.w, h3, l3);
      ghi[r * HSS + c + 0] = h0; glo[r * HSS + c + 0] = l0;
      ghi[r * HSS + c + 1] = h1; glo[r * HSS + c + 1] = l1;
      ghi[r * HSS + c + 2] = h2; glo[r * HSS + c + 2] = l2;
      ghi[r * HSS + c + 3] = h3; glo[r * HSS + c + 3] = l3;
    } else if (c < 256) {
      v = *(const float4*)&eb[(long)b * ND + (c - 128)];
    } else if (c < 320) {
      v = *(const float4*)&edge_enc[(long)b * 64 + (c - 256)];
    } else {
      float vv[4];
#pragma unroll
      for (int q = 0; q < 4; ++q) {
        int cc = c + q - 320;
        vv[q] = (cc == 0) ? 0.f : time_emb[b * 32 + cc];
      }
      v = make_float4(vv[0], vv[1], vv[2], vv[3]);
    }
    union { bf16 h[4]; uint2 u; } pk;
    pk.h[0] = (bf16)v.x; pk.h[1] = (bf16)v.y; pk.h[2] = (bf16)v.z; pk.h[3] = (bf16)v.w;
    *(uint2*)&xs[r * XSS + c] = pk.u;
  }
  __syncthreads();

  const int wid = tid >> 6, lane = tid & 63;
  const int colq = lane & 15, cq = lane >> 4;
  const int rsub = cq * 4;

  const bf16* W1l = W1blk + layer * 90112 + (wid * 64 + colq) * 32 + cq * 8;
  const bf16* xsl = xs + colq * XSS + cq * 8;
  f32x4 acc[4][4];
#pragma unroll
  for (int m = 0; m < 4; ++m)
#pragma unroll
    for (int n = 0; n < 4; ++n) acc[m][n] = (f32x4){0.f, 0.f, 0.f, 0.f};
#pragma unroll
  for (int k0 = 0; k0 < 11; ++k0) {
    bf16x8 a[4], b[4];
#pragma unroll
    for (int m = 0; m < 4; ++m) a[m] = *(const bf16x8*)(xsl + m * 16 * XSS + k0 * 32);
#pragma unroll
    for (int n = 0; n < 4; ++n) b[n] = *(const bf16x8*)(W1l + k0 * 8192 + n * 512);
#pragma unroll
    for (int m = 0; m < 4; ++m)
#pragma unroll
      for (int n = 0; n < 4; ++n) acc[m][n] = MFMA16(a[m], b[n], acc[m][n]);
  }
  __syncthreads();

  const float* w320l = w320 + layer * 256;
  const float* b1l = b1 + layer * 256;
#pragma unroll
  for (int n = 0; n < 4; ++n) {
    int cg = wid * 64 + n * 16 + colq;
    float wv = w320l[cg], bv = b1l[cg];
#pragma unroll
    for (int m = 0; m < 4; ++m)
#pragma unroll
      for (int i = 0; i < 4; ++i) {
        int r = m * 16 + rsub + i;
        acc[m][n][i] = fmaxf(acc[m][n][i] + cl[r] * wv + bv, 0.f);
      }
  }
  if (wid < 2) {
#pragma unroll
    for (int m = 0; m < 4; ++m)
#pragma unroll
      for (int n = 0; n < 4; ++n)
#pragma unroll
        for (int i = 0; i < 4; ++i) {
          int r = m * 16 + rsub + i;
          int cc = wid * 64 + n * 16 + colq;
          bf16 hi, lo; split2(acc[m][n][i], hi, lo);
          hhi[r * HSS + cc] = hi;
          hlo[r * HSS + cc] = lo;
        }
  }
  __syncthreads();

  const bf16* W2h = W2blk + layer * 65536 + (wid * 32 + colq) * 32 + cq * 8;
  const bf16* W2l = W2h + 32768;
  const bf16* hhil = hhi + colq * HSS + cq * 8;
  const bf16* hlol = hlo + colq * HSS + cq * 8;
  f32x4 acc2[4][2];
#pragma unroll
  for (int m = 0; m < 4; ++m)
#pragma unroll
    for (int n = 0; n < 2; ++n) acc2[m][n] = (f32x4){0.f, 0.f, 0.f, 0.f};
#pragma unroll
  for (int kg = 0; kg < 8; ++kg) {
    if (kg == 4) {
      __syncthreads();
      if (wid >= 2) {
#pragma unroll
        for (int m = 0; m < 4; ++m)
#pragma unroll
          for (int n = 0; n < 4; ++n)
#pragma unroll
            for (int i = 0; i < 4; ++i) {
              int r = m * 16 + rsub + i;
              int cc = (wid & 1) * 64 + n * 16 + colq;
              bf16 hi, lo; split2(acc[m][n][i], hi, lo);
              hhi[r * HSS + cc] = hi;
              hlo[r * HSS + cc] = lo;
            }
      }
      __syncthreads();
    }
    int lk = (kg & 3) * 32;
    bf16x8 ahi[4], alo[4], bhi[2], blo[2];
#pragma unroll
    for (int m = 0; m < 4; ++m) {
      ahi[m] = *(const bf16x8*)(hhil + m * 16 * HSS + lk);
      alo[m] = *(const bf16x8*)(hlol + m * 16 * HSS + lk);
    }
#pragma unroll
    for (int n = 0; n < 2; ++n) {
      bhi[n] = *(const bf16x8*)(W2h + kg * 4096 + n * 512);
      blo[n] = *(const bf16x8*)(W2l + kg * 4096 + n * 512);
    }
#pragma unroll
    for (int m = 0; m < 4; ++m)
#pragma unroll
      for (int n = 0; n < 2; ++n) {
        acc2[m][n] = MFMA16(ahi[m], bhi[n], acc2[m][n]);
        acc2[m][n] = MFMA16(ahi[m], blo[n], acc2[m][n]);
        acc2[m][n] = MFMA16(alo[m], bhi[n], acc2[m][n]);
      }
  }
  __syncthreads();

  const float* b2l = b2 + layer * 128;
  const float* nbl = nb_out + ((long)(layer * 2 + side)) * NB_EV * ND;
#pragma unroll
  for (int n = 0; n < 2; ++n) {
    int cg = wid * 32 + n * 16 + colq;
    float bv = b2l[cg];
#pragma unroll
    for (int m = 0; m < 4; ++m)
#pragma unroll
      for (int i = 0; i < 4; ++i) {
        int r = m * 16 + rsub + i;
        float mval = acc2[m][n][i] + bv + nbl[(long)(b0r + r) * ND + cg];
        bf16 hi, lo; split2(mval, hi, lo);
        mhi[r * HSS + cg] = hi;
        mlo[r * HSS + cg] = lo;
      }
  }
  __syncthreads();

  float* outP = side ? outB : outA;
  const int ostride = side ? ostrideB : ostrideA;
  const int rowA = wid * 16 + colq;
  const int rbase = wid * 16 + rsub;
  const bf16* mhil = mhi + rowA * HSS + cq * 8;
  const bf16* mlol = mlo + rowA * HSS + cq * 8;
  const bf16* ghil = ghi + rowA * HSS + cq * 8;
  const bf16* glol = glo + rowA * HSS + cq * 8;
  const bf16* wihl = wihblk + colq * 32 + cq * 8;
  const bf16* whhl = whhblk + colq * 32 + cq * 8;

  for (int jt = 0; jt < 8; ++jt) {
    f32x4 gx[3], gh[3];
#pragma unroll
    for (int g = 0; g < 3; ++g) {
      gx[g] = (f32x4){0.f, 0.f, 0.f, 0.f};
      gh[g] = (f32x4){0.f, 0.f, 0.f, 0.f};
    }
#pragma unroll
    for (int kc = 0; kc < 4; ++kc) {
      bf16x8 amh = *(const bf16x8*)(mhil + kc * 32);
      bf16x8 aml = *(const bf16x8*)(mlol + kc * 32);
      bf16x8 ahh = *(const bf16x8*)(ghil + kc * 32);
      bf16x8 ahl = *(const bf16x8*)(glol + kc * 32);
#pragma unroll
      for (int g = 0; g < 3; ++g) {
        int nb = (g * 128 + jt * 16) * 32;
        bf16x8 bh = *(const bf16x8*)(wihl + kc * 12288 + nb);
        bf16x8 bl = *(const bf16x8*)(wihl + 49152 + kc * 12288 + nb);
        gx[g] = MFMA16(amh, bh, gx[g]);
        gx[g] = MFMA16(aml, bh, gx[g]);
        gx[g] = MFMA16(amh, bl, gx[g]);
        bf16x8 ch = *(const bf16x8*)(whhl + kc * 12288 + nb);
        bf16x8 cl2 = *(const bf16x8*)(whhl + 49152 + kc * 12288 + nb);
        gh[g] = MFMA16(ahh, ch, gh[g]);
        gh[g] = MFMA16(ahl, ch, gh[g]);
        gh[g] = MFMA16(ahh, cl2, gh[g]);
      }
    }
    int j = jt * 16 + colq;
    float bihr = bih[j], bihz = bih[128 + j], bihn = bih[256 + j];
    float bhhr = bhh[j], bhhz = bhh[128 + j], bhhn = bhh[256 + j];
#pragma unroll
    for (int i = 0; i < 4; ++i) {
      int rr = rbase + i;
      float rx = gx[0][i] + bihr, zx = gx[1][i] + bihz, nx = gx[2][i] + bihn;
      float rh = gh[0][i] + bhhr, zh = gh[1][i] + bhhz, nh = gh[2][i] + bhhn;
      float r = 1.f / (1.f + expf(-(rx + rh)));
      float zz = 1.f / (1.f + expf(-(zx + zh)));
      float n = tanhf(nx + r * nh);
      float hval = (float)ghi[rr * HSS + j] + (float)glo[rr * HSS + j];
      outP[(long)(b0r + rr) * ostride + j] = (1.f - zz) * n + zz * hval;
    }
  }
}

// ---------------- launch ----------------
extern "C" void kernel_launch(void* const* d_in, const int* in_sizes, int n_in,
                              void* d_out, int out_size, void* d_ws, size_t ws_size,
                              hipStream_t stream) {
  const int* srcn = (const int*)d_in[0];
  const int* dstn = (const int*)d_in[1];
  const float* edge_attrs = (const float*)d_in[2];
  const float* timestamps = (const float*)d_in[3];
  const float* memory = (const float*)d_in[4];
  const int* neighbor_ids = (const int*)d_in[5];
  const float* neighbor_times = (const float*)d_in[6];
  const float* neighbor_edge_attrs = (const float*)d_in[7];
  const float* t2v_w0 = (const float*)d_in[8];
  const float* t2v_b0 = (const float*)d_in[9];
  const float* t2v_w = (const float*)d_in[10];
  const float* t2v_b = (const float*)d_in[11];
  const float* enc_W = (const float*)d_in[12];
  const float* enc_b = (const float*)d_in[13];
  const float* mlp_W1 = (const float*)d_in[14];
  const float* mlp_b1 = (const float*)d_in[15];
  const float* mlp_W2 = (const float*)d_in[16];
  const float* mlp_b2 = (const float*)d_in[17];
  const float* gru_w_ih = (const float*)d_in[18];
  const float* gru_w_hh = (const float*)d_in[19];
  const float* gru_b_ih = (const float*)d_in[20];
  const float* gru_b_hh = (const float*)d_in[21];

  char* ws = (char*)d_ws;
  size_t off = 0;
  auto alloc = [&](size_t bytes) { size_t o = off; off += (bytes + 255) & ~(size_t)255; return o; };
  bf16* W1blk = (bf16*)(ws + alloc((size_t)2 * 11 * 256 * 32 * 2));
  bf16* W1red = (bf16*)(ws + alloc((size_t)2 * 7 * 256 * 32 * 2));
  bf16* W2blk = (bf16*)(ws + alloc((size_t)2 * 2 * 8 * 128 * 32 * 2));
  bf16* wihblk = (bf16*)(ws + alloc((size_t)2 * 4 * 384 * 32 * 2));
  bf16* whhblk = (bf16*)(ws + alloc((size_t)2 * 4 * 384 * 32 * 2));
  float* w320 = (float*)(ws + alloc(512 * 4));
  float* time_emb = (float*)(ws + alloc((size_t)NB_EV * 32 * 4));
  float* edge_enc = (float*)(ws + alloc((size_t)NB_EV * 64 * 4));
  float* embA0 = (float*)(ws + alloc((size_t)NB_EV * ND * 4));
  float* embB0 = (float*)(ws + alloc((size_t)NB_EV * ND * 4));
  float* embA1 = (float*)(ws + alloc((size_t)NB_EV * ND * 4));
  float* embB1 = (float*)(ws + alloc((size_t)NB_EV * ND * 4));
  float* nb_out = (float*)(ws + alloc((size_t)4 * NB_EV * ND * 4));
  float* Hnode = (float*)(ws + alloc((size_t)4 * NB_EV * 256 * 4));
  bf16* memB = (bf16*)(ws + alloc((size_t)N_NODES * ND * 2));
  bf16* Xlin = (bf16*)(ws + alloc((size_t)2 * ROWS_NB * 96 * 2));
  int* nbidArr = (int*)(ws + alloc((size_t)2 * ROWS_NB * 4));
  float* clArr = (float*)(ws + alloc((size_t)2 * ROWS_NB * 4));

  k_prep_all<<<2048, 256, 0, stream>>>(
      mlp_W1, mlp_W2, gru_w_ih, gru_w_hh,
      timestamps, t2v_w0, t2v_b0, t2v_w, t2v_b,
      srcn, dstn, memory, edge_attrs, enc_W, enc_b,
      W1blk, W1red, W2blk, wihblk, whhblk, w320,
      time_emb, embA0, embB0, memB, edge_enc);
  k_prep_nbr<<<dim3(2560, 2, 1), 256, 0, stream>>>(
      srcn, dstn, neighbor_ids, neighbor_times, neighbor_edge_attrs,
      t2v_w0, t2v_b0, t2v_w, t2v_b, Xlin, nbidArr, clArr);
  k_hnode<<<dim3(128, 4, 1), 256, 0, stream>>>(srcn, dstn, memory, W1blk, Hnode);

  k_nbr<<<dim3(ROWS_NB / 80, 2, 1), 256, 0, stream>>>(
      memB, nbidArr, clArr, Xlin, Hnode, W1red, W2blk, w320, mlp_b1, mlp_b2, nb_out);

  k_event<<<2 * NB_EV / 64, 256, 0, stream>>>(
      0, embA0, embB0, embA1, ND, embB1, ND, time_emb, edge_enc,
      W1blk, W2blk, w320, mlp_b1, mlp_b2, nb_out,
      wihblk, whhblk, gru_b_ih, gru_b_hh);

  float* outf = (float*)d_out;
  k_event<<<2 * NB_EV / 64, 256, 0, stream>>>(
      1, embA1, embB1, outf, 2 * ND, outf + ND, 2 * ND, time_emb, edge_enc,
      W1blk, W2blk, w320, mlp_b1, mlp_b2, nb_out,
      wihblk, whhblk, gru_b_ih, gru_b_hh);
}